// Round 1
// baseline (296.835 us; speedup 1.0000x reference)
//
#include <hip/hip_runtime.h>
#include <hip/hip_bf16.h>

#define NUSERS 100000
#define NITEMS 50000
#define NEDGE  1000000
#define NBATCH 16384
#define CAP_LU 320000     // filtered like-edges of batch users; expected ~164K (2x margin)
#define EPB    2048       // edges per block in passA/passC (8 per thread)
#define NBLK_E ((NEDGE + EPB - 1) / EPB)   // 489
#define NBW    3125       // NUSERS/32 bitmask words
#define GGRID  2048       // persistent grid: 256 CU x 8 blocks (256thr) = full residency

// ---- workspace layout, units of 4 bytes; total 8,979,016 units = 35.9 MB ----
// Overlays:
//   uembh (bf16 uemb shadow, 3.2M units) = [530,440 .. 3,730,440): covers
//     partLI+partLU+partSD (dead after passD; k_cvt runs after passD) + pad.
//   soc1  (bf16, 3.2M units) = [3,730,440 .. 6,930,440): covers csrli (dead after
//     gather_item) + csrlu + ri1 (dead after batch_rat) + pad. gather_soc runs
//     after batch_rat. csrsd/ru1c/ru2c live beyond both overlays.
#define OFF_GC     0                          // 256*3 bucket counts (memset 0)
#define OFF_GB     768
#define OFF_GCUR   1536
#define OFF_BITS   2304                       // 3136 u32 batch-membership bitmask
#define OFF_NEED   (OFF_BITS + 3136)          // NUSERS bytes = 25000 units
#define OFF_ZEND   (OFF_NEED + NUSERS / 4)    // 30,440 end of memset-0 region
#define OFF_IDEG   OFF_ZEND
#define OFF_UDEG   (OFF_IDEG + NITEMS)
#define OFF_SDEG   (OFF_UDEG + NUSERS)
#define OFF_ISTART (OFF_SDEG + NUSERS)
#define OFF_USTART (OFF_ISTART + NITEMS)
#define OFF_SSTART (OFF_USTART + NUSERS)
#define OFF_PARTLI (OFF_SSTART + NUSERS)      // 530,440
#define OFF_PARTLU (OFF_PARTLI + NEDGE)
#define OFF_PARTSD (OFF_PARTLU + CAP_LU)
#define OFF_UEMBH  OFF_PARTLI                 // NUSERS*32 units (bf16 shadow)
#define OFF_CSRLI  (OFF_UEMBH + NUSERS * 32)  // 3,730,440
#define OFF_CSRLU  (OFF_CSRLI + NEDGE)
#define OFF_RI1    (OFF_CSRLU + CAP_LU)       // NITEMS*32 units (bf16)
#define OFF_SOC1   OFF_CSRLI                  // NUSERS*32 units overlay
#define OFF_CSRSD  (OFF_SOC1 + NUSERS * 32)   // 6,930,440 (LIVE till k_final)
#define OFF_RU1C   (OFF_CSRSD + NEDGE)        // NBATCH*64 bf16 = 524,288 units
#define OFF_RU2C   (OFF_RU1C + NBATCH * 32)
#define WS_FLOATS  (OFF_RU2C + NBATCH * 32)   // 8,979,016

typedef unsigned short u16;

__device__ __forceinline__ float bf2f(u16 h) {
    union { unsigned u; float f; } c; c.u = ((unsigned)h) << 16; return c.f;
}
__device__ __forceinline__ u16 f2bf(float f) {
    union { float f; unsigned u; } c; c.f = f;
    unsigned r = c.u + 0x7fffu + ((c.u >> 16) & 1u);   // RNE
    return (u16)(r >> 16);
}
__device__ __forceinline__ void acc2(unsigned w, float& a0, float& a1) {
    a0 += bf2f((u16)(w & 0xffff));
    a1 += bf2f((u16)(w >> 16));
}

// ---- batch membership: bitmask + needed flags ----
__global__ void k_slot(const int* __restrict__ users, unsigned* __restrict__ bits,
                       unsigned char* __restrict__ needed) {
    int b = blockIdx.x * blockDim.x + threadIdx.x;
    if (b < NBATCH) {
        int u = users[b];
        atomicOr(&bits[u >> 5], 1u << (u & 31));
        needed[u] = 1;
    }
}

// ---- pass A: per-block LDS bucket histograms; membership via LDS bitmask ----
__global__ void k_passA(const int* __restrict__ lu, const int* __restrict__ li,
                        const int* __restrict__ sd, const int* __restrict__ ss,
                        const unsigned* __restrict__ bits, int* __restrict__ gcnt,
                        unsigned char* __restrict__ needed) {
    __shared__ int lc[768];
    __shared__ unsigned sbits[NBW];
    int t = threadIdx.x;
    for (int k = t; k < 768; k += 256) lc[k] = 0;
    for (int k = t; k < NBW; k += 256) sbits[k] = bits[k];
    __syncthreads();
    int base = blockIdx.x * EPB;
    int end = base + EPB; if (end > NEDGE) end = NEDGE;
    for (int e = base + t; e < end; e += 256) {
        int item = li[e], a = lu[e], d = sd[e];
        atomicAdd(&lc[item >> 9], 1);                        // list0: by item
        if ((sbits[a >> 5] >> (a & 31)) & 1)                 // list1: batch users
            atomicAdd(&lc[256 + (a >> 9)], 1);
        atomicAdd(&lc[512 + (d >> 9)], 1);                   // list2: by dst user
        if ((sbits[d >> 5] >> (d & 31)) & 1)                 // soc1 needed at source
            needed[ss[e]] = 1;
    }
    __syncthreads();
    for (int k = t; k < 768; k += 256)
        if (lc[k]) atomicAdd(&gcnt[k], lc[k]);
}

// ---- pass B: one block; 3 exclusive scans of 256 bucket counts ----
__global__ void k_passB(const int* __restrict__ gcnt, int* __restrict__ gbase,
                        int* __restrict__ gcur) {
    __shared__ int s[256];
    int t = threadIdx.x;
    for (int j = 0; j < 3; ++j) {
        int v = gcnt[j * 256 + t];
        s[t] = v;
        __syncthreads();
        for (int o = 1; o < 256; o <<= 1) {
            int x = (t >= o) ? s[t - o] : 0;
            __syncthreads();
            s[t] += x;
            __syncthreads();
        }
        int ex = s[t] - v;
        gbase[j * 256 + t] = ex;
        gcur[j * 256 + t] = ex;
        __syncthreads();
    }
}

// ---- pass C: partition edges into per-bucket chunks; membership via LDS
//      bitmask in phase 1, cached in a register mask for phase 2 ----
__global__ void k_passC(const int* __restrict__ lu, const int* __restrict__ li,
                        const int* __restrict__ sd, const int* __restrict__ ss,
                        const unsigned* __restrict__ bits, int* __restrict__ gcur,
                        int* __restrict__ partLI, int* __restrict__ partLU,
                        int* __restrict__ partSD) {
    __shared__ int lc[768];   // local counts, then rank counters
    __shared__ int go[768];   // this block's global chunk offsets
    __shared__ unsigned sbits[NBW];
    int t = threadIdx.x;
    for (int k = t; k < 768; k += 256) lc[k] = 0;
    for (int k = t; k < NBW; k += 256) sbits[k] = bits[k];
    __syncthreads();
    int base = blockIdx.x * EPB;
    int end = base + EPB; if (end > NEDGE) end = NEDGE;
    unsigned mask = 0;        // bit i: edge (base + i*256 + t) belongs to a batch user
    int i = 0;
    for (int e = base + t; e < end; e += 256, ++i) {
        int item = li[e], a = lu[e], d = sd[e];
        atomicAdd(&lc[item >> 9], 1);
        if ((sbits[a >> 5] >> (a & 31)) & 1) {
            atomicAdd(&lc[256 + (a >> 9)], 1);
            mask |= (1u << i);
        }
        atomicAdd(&lc[512 + (d >> 9)], 1);
    }
    __syncthreads();
    for (int k = t; k < 768; k += 256) {
        go[k] = lc[k] ? atomicAdd(&gcur[k], lc[k]) : 0;
        lc[k] = 0;
    }
    __syncthreads();
    i = 0;
    for (int e = base + t; e < end; e += 256, ++i) {
        int item = li[e], a = lu[e], d = sd[e], s_ = ss[e];
        int b0 = item >> 9;
        int r0 = atomicAdd(&lc[b0], 1);
        partLI[go[b0] + r0] = (a << 9) | (item & 511);
        if (mask & (1u << i)) {
            int b1 = 256 + (a >> 9);
            int r1 = atomicAdd(&lc[b1], 1);
            partLU[go[b1] + r1] = (item << 9) | (a & 511);
        }
        int b2 = 512 + (d >> 9);
        int r2 = atomicAdd(&lc[b2], 1);
        partSD[go[b2] + r2] = (s_ << 9) | (d & 511);
    }
}

// ---- pass D: one block per bucket; count/scan -> deg/start + rank-scatter ----
__global__ void k_passD(const int* __restrict__ gcnt, const int* __restrict__ gbase,
                        const int* __restrict__ partLI, const int* __restrict__ partLU,
                        const int* __restrict__ partSD, int* __restrict__ csrli,
                        int* __restrict__ csrlu, int* __restrict__ csrsd,
                        int* __restrict__ ideg, int* __restrict__ udeg,
                        int* __restrict__ sdeg, int* __restrict__ istart,
                        int* __restrict__ ustart, int* __restrict__ sstart) {
    __shared__ int lcnt[512], lstart[512], sb[2][512];
    int t = threadIdx.x;
    int blk = blockIdx.x, list, b;
    const int* part; int* csr; int* deg; int* start; int n;
    if (blk < 196)      { list = 0; b = blk;       part = partLI; csr = csrli; deg = ideg; start = istart; n = NITEMS; }
    else if (blk < 392) { list = 1; b = blk - 196; part = partLU; csr = csrlu; deg = udeg; start = ustart; n = NUSERS; }
    else                { list = 2; b = blk - 392; part = partSD; csr = csrsd; deg = sdeg; start = sstart; n = NUSERS; }
    int base = gbase[list * 256 + b], cnt = gcnt[list * 256 + b];
    int node0 = b << 9;
    int M = n - node0; if (M > 512) M = 512; if (M < 0) M = 0;

    lcnt[t] = 0; lcnt[t + 256] = 0;
    __syncthreads();
    for (int i = t; i < cnt; i += 256) atomicAdd(&lcnt[part[base + i] & 511], 1);
    __syncthreads();
    sb[0][t] = lcnt[t]; sb[0][t + 256] = lcnt[t + 256];
    __syncthreads();
    int pp = 0;
    for (int o = 1; o < 512; o <<= 1) {
        int np = pp ^ 1;
        for (int k = t; k < 512; k += 256) {
            int v = sb[pp][k];
            if (k >= o) v += sb[pp][k - o];
            sb[np][k] = v;
        }
        __syncthreads();
        pp = np;
    }
    for (int k = t; k < 512; k += 256) {
        int ex = sb[pp][k] - lcnt[k];       // exclusive scan
        lstart[k] = ex;
        if (k < M) { deg[node0 + k] = lcnt[k]; start[node0 + k] = base + ex; }
    }
    __syncthreads();
    lcnt[t] = 0; lcnt[t + 256] = 0;
    __syncthreads();
    for (int i = t; i < cnt; i += 256) {
        int p = part[base + i];
        int nl = p & 511;
        int r = atomicAdd(&lcnt[nl], 1);
        csr[base + lstart[nl] + r] = p >> 9;  // window stays in one XCD's L2
    }
}

// ---- bf16 shadow of uemb (runs after passD; overlays dead part*) ----
__global__ void k_cvt(const float* __restrict__ src, u16* __restrict__ dst) {
    int t = blockIdx.x * 256 + threadIdx.x;
    if (t >= NUSERS * 16) return;                 // 16 float4 per row
    float4 v = ((const float4*)src)[t];
    ushort4 o;
    o.x = f2bf(v.x); o.y = f2bf(v.y); o.z = f2bf(v.z); o.w = f2bf(v.w);
    ((ushort4*)dst)[t] = o;
}

// ---- ri1 = i_sw*iemb + mean(uembh[liking users]); persistent waves, TWO items
//      per wave. Whole adjacency list fetched with ONE lane-parallel csr load
//      (deg<=64 covers Poisson(20) essentially always), indices broadcast via
//      __shfl, gathers fully predicated -> no serial csr/tail round trips. ----
__global__ void k_gather_item(const float* __restrict__ iemb,
                              const unsigned* __restrict__ uh32,
                              const int* __restrict__ csr, const int* __restrict__ istart,
                              const int* __restrict__ ideg, unsigned* __restrict__ ri1) {
    int lane = threadIdx.x & 63;
    int wid  = blockIdx.x * 4 + (threadIdx.x >> 6);
    int nw   = gridDim.x * 4;
    int half = lane >> 5, l = lane & 31;
    for (int nA = wid * 2; nA < NITEMS; nA += nw * 2) {
        int nB = nA + 1;                          // NITEMS even -> always valid
        int jA = istart[nA], dA = ideg[nA];
        int jB = istart[nB], dB = ideg[nB];
        int cA = (lane < dA) ? csr[jA + lane] : 0;
        int cB = (lane < dB) ? csr[jB + lane] : 0;
        float a0=0.f,b0=0.f,a1=0.f,b1=0.f,a2=0.f,b2=0.f,a3=0.f,b3=0.f;
        float e0a=0.f,f0a=0.f,e1a=0.f,f1a=0.f,e2a=0.f,f2a=0.f,e3a=0.f,f3a=0.f;
        int kmA = dA < 64 ? dA : 64;
        int kmB = dB < 64 ? dB : 64;
        int km = kmA > kmB ? kmA : kmB;
        for (int k = 0; k < km; k += 8) {         // 8 entries/node/iter, 8 gathers in flight
            int q0 = k + half, q1 = k + 2 + half, q2 = k + 4 + half, q3 = k + 6 + half;
            int rA0 = __shfl(cA, q0), rA1 = __shfl(cA, q1);
            int rA2 = __shfl(cA, q2), rA3 = __shfl(cA, q3);
            int rB0 = __shfl(cB, q0), rB1 = __shfl(cB, q1);
            int rB2 = __shfl(cB, q2), rB3 = __shfl(cB, q3);
            if (q0 < kmA) acc2(uh32[rA0 * 32 + l], a0, b0);
            if (q1 < kmA) acc2(uh32[rA1 * 32 + l], a1, b1);
            if (q2 < kmA) acc2(uh32[rA2 * 32 + l], a2, b2);
            if (q3 < kmA) acc2(uh32[rA3 * 32 + l], a3, b3);
            if (q0 < kmB) acc2(uh32[rB0 * 32 + l], e0a, f0a);
            if (q1 < kmB) acc2(uh32[rB1 * 32 + l], e1a, f1a);
            if (q2 < kmB) acc2(uh32[rB2 * 32 + l], e2a, f2a);
            if (q3 < kmB) acc2(uh32[rB3 * 32 + l], e3a, f3a);
        }
        for (int j = jA + 64; j < jA + dA; j += 2) {   // deg>64 tail (rare)
            int idx = j + half;
            if (idx < jA + dA) acc2(uh32[csr[idx] * 32 + l], a0, b0);
        }
        for (int j = jB + 64; j < jB + dB; j += 2) {
            int idx = j + half;
            if (idx < jB + dB) acc2(uh32[csr[idx] * 32 + l], e0a, f0a);
        }
        float sA0 = (a0 + a1) + (a2 + a3);
        float sA1 = (b0 + b1) + (b2 + b3);
        float sB0 = (e0a + e1a) + (e2a + e3a);
        float sB1 = (f0a + f1a) + (f2a + f3a);
        sA0 += __shfl_xor(sA0, 32); sA1 += __shfl_xor(sA1, 32);
        sB0 += __shfl_xor(sB0, 32); sB1 += __shfl_xor(sB1, 32);
        if (half == 0) {
            float dgf = (float)dA;
            float inv = 1.0f / fmaxf(dgf, 1.0f);
            float sw = 1.0f - dgf / (dgf + 1e-8f);
            float2 ev = ((const float2*)(iemb + nA * 64))[l];
            ri1[nA * 32 + l] = (unsigned)f2bf(sw * ev.x + sA0 * inv)
                             | ((unsigned)f2bf(sw * ev.y + sA1 * inv) << 16);
            float dgg = (float)dB;
            float inv2 = 1.0f / fmaxf(dgg, 1.0f);
            float sw2 = 1.0f - dgg / (dgg + 1e-8f);
            float2 ev2 = ((const float2*)(iemb + nB * 64))[l];
            ri1[nB * 32 + l] = (unsigned)f2bf(sw2 * ev2.x + sB0 * inv2)
                             | ((unsigned)f2bf(sw2 * ev2.y + sB1 * inv2) << 16);
        }
    }
}

// ---- batch rating means: ru1c[b]=mean(iemb[li]), ru2c[b]=mean(ri1[li]).
//      Lane-parallel csr fetch + shfl broadcast; 4 rows (8 loads) in flight. ----
__global__ void k_batch_rat(const int* __restrict__ users, const float* __restrict__ iemb,
                            const u16* __restrict__ ri1, const int* __restrict__ csr,
                            const int* __restrict__ ustart, const int* __restrict__ udeg,
                            u16* __restrict__ ru1c, u16* __restrict__ ru2c) {
    int lane = threadIdx.x & 63;
    int wid  = blockIdx.x * 4 + (threadIdx.x >> 6);
    int nw   = gridDim.x * 4;
    for (int b = wid; b < NBATCH; b += nw) {
        int u = users[b];
        int j0 = ustart[u], dg = udeg[u];
        int cv = (lane < dg) ? csr[j0 + lane] : 0;
        float p0=0.f,p1=0.f,p2=0.f,p3=0.f, q0=0.f,q1=0.f,q2=0.f,q3=0.f;
        int km = dg < 64 ? dg : 64;
        for (int k = 0; k < km; k += 4) {
            int i0 = __shfl(cv, k),     i1 = __shfl(cv, k + 1);
            int i2 = __shfl(cv, k + 2), i3 = __shfl(cv, k + 3);
            p0 += iemb[i0 * 64 + lane]; q0 += bf2f(ri1[i0 * 64 + lane]);
            if (k + 1 < km) { p1 += iemb[i1 * 64 + lane]; q1 += bf2f(ri1[i1 * 64 + lane]); }
            if (k + 2 < km) { p2 += iemb[i2 * 64 + lane]; q2 += bf2f(ri1[i2 * 64 + lane]); }
            if (k + 3 < km) { p3 += iemb[i3 * 64 + lane]; q3 += bf2f(ri1[i3 * 64 + lane]); }
        }
        for (int j = j0 + 64; j < j0 + dg; ++j) {      // deg>64 tail (rare)
            int i0 = csr[j];
            p0 += iemb[i0 * 64 + lane]; q0 += bf2f(ri1[i0 * 64 + lane]);
        }
        float inv = 1.0f / fmaxf((float)dg, 1.0f);
        ru1c[b * 64 + lane] = f2bf(((p0 + p1) + (p2 + p3)) * inv);
        ru2c[b * 64 + lane] = f2bf(((q0 + q1) + (q2 + q3)) * inv);
    }
}

// ---- soc1 = mean(uembh[social sources]); only where needed; persistent waves,
//      TWO nodes per wave, lane-parallel csr + shfl broadcast as gather_item. ----
__global__ void k_gather_soc(const unsigned* __restrict__ uh32,
                             const int* __restrict__ csr, const int* __restrict__ sstart,
                             const int* __restrict__ sdeg,
                             const unsigned char* __restrict__ needed,
                             unsigned* __restrict__ soc1) {
    int lane = threadIdx.x & 63;
    int wid  = blockIdx.x * 4 + (threadIdx.x >> 6);
    int nw   = gridDim.x * 4;
    int half = lane >> 5, l = lane & 31;
    for (int nA = wid * 2; nA < NUSERS; nA += nw * 2) {
        int nB = nA + 1;                          // NUSERS even -> always valid
        unsigned short nd = *(const unsigned short*)(needed + nA);   // nA even
        if (!nd) continue;                        // neither row ever read
        int needA = nd & 0xff, needB = nd >> 8;
        int jA = sstart[nA], dA = needA ? sdeg[nA] : 0;
        int jB = sstart[nB], dB = needB ? sdeg[nB] : 0;
        int cA = (lane < dA) ? csr[jA + lane] : 0;
        int cB = (lane < dB) ? csr[jB + lane] : 0;
        float a0=0.f,b0=0.f,a1=0.f,b1=0.f,a2=0.f,b2=0.f,a3=0.f,b3=0.f;
        float e0a=0.f,f0a=0.f,e1a=0.f,f1a=0.f,e2a=0.f,f2a=0.f,e3a=0.f,f3a=0.f;
        int kmA = dA < 64 ? dA : 64;
        int kmB = dB < 64 ? dB : 64;
        int km = kmA > kmB ? kmA : kmB;
        for (int k = 0; k < km; k += 8) {
            int q0 = k + half, q1 = k + 2 + half, q2 = k + 4 + half, q3 = k + 6 + half;
            int rA0 = __shfl(cA, q0), rA1 = __shfl(cA, q1);
            int rA2 = __shfl(cA, q2), rA3 = __shfl(cA, q3);
            int rB0 = __shfl(cB, q0), rB1 = __shfl(cB, q1);
            int rB2 = __shfl(cB, q2), rB3 = __shfl(cB, q3);
            if (q0 < kmA) acc2(uh32[rA0 * 32 + l], a0, b0);
            if (q1 < kmA) acc2(uh32[rA1 * 32 + l], a1, b1);
            if (q2 < kmA) acc2(uh32[rA2 * 32 + l], a2, b2);
            if (q3 < kmA) acc2(uh32[rA3 * 32 + l], a3, b3);
            if (q0 < kmB) acc2(uh32[rB0 * 32 + l], e0a, f0a);
            if (q1 < kmB) acc2(uh32[rB1 * 32 + l], e1a, f1a);
            if (q2 < kmB) acc2(uh32[rB2 * 32 + l], e2a, f2a);
            if (q3 < kmB) acc2(uh32[rB3 * 32 + l], e3a, f3a);
        }
        for (int j = jA + 64; j < jA + dA; j += 2) {   // deg>64 tail (rare)
            int idx = j + half;
            if (idx < jA + dA) acc2(uh32[csr[idx] * 32 + l], a0, b0);
        }
        for (int j = jB + 64; j < jB + dB; j += 2) {
            int idx = j + half;
            if (idx < jB + dB) acc2(uh32[csr[idx] * 32 + l], e0a, f0a);
        }
        float sA0 = (a0 + a1) + (a2 + a3);
        float sA1 = (b0 + b1) + (b2 + b3);
        float sB0 = (e0a + e1a) + (e2a + e3a);
        float sB1 = (f0a + f1a) + (f2a + f3a);
        sA0 += __shfl_xor(sA0, 32); sA1 += __shfl_xor(sA1, 32);
        sB0 += __shfl_xor(sB0, 32); sB1 += __shfl_xor(sB1, 32);
        if (half == 0) {
            if (needA) {
                float inv = 1.0f / fmaxf((float)dA, 1.0f);
                soc1[nA * 32 + l] = (unsigned)f2bf(sA0 * inv)
                                  | ((unsigned)f2bf(sA1 * inv) << 16);
            }
            if (needB) {
                float inv = 1.0f / fmaxf((float)dB, 1.0f);
                soc1[nB * 32 + l] = (unsigned)f2bf(sB0 * inv)
                                  | ((unsigned)f2bf(sB1 * inv) << 16);
            }
        }
    }
}

// ---- fused batch social mean + epilogue; lane-parallel csr + shfl broadcast ----
__global__ void k_final(const int* __restrict__ users, const int* __restrict__ items,
                        const float* __restrict__ uemb, const float* __restrict__ iemb,
                        const u16* __restrict__ soc1, const int* __restrict__ csr,
                        const int* __restrict__ sstart, const int* __restrict__ sdeg,
                        const u16* __restrict__ ru1c, const u16* __restrict__ ru2c,
                        const int* __restrict__ udeg, float* __restrict__ out) {
    int d   = threadIdx.x & 63;
    int wid = blockIdx.x * 4 + (threadIdx.x >> 6);
    int nw  = gridDim.x * 4;
    for (int b = wid; b < NBATCH; b += nw) {
        int u = users[b], it = items[b];
        int j0 = sstart[u], dg = sdeg[u];
        int cv = (d < dg) ? csr[j0 + d] : 0;
        float s0=0.f, s1a=0.f, s2a=0.f, s3a=0.f;
        int km = dg < 64 ? dg : 64;
        for (int k = 0; k < km; k += 4) {
            int c0 = __shfl(cv, k),     c1 = __shfl(cv, k + 1);
            int c2 = __shfl(cv, k + 2), c3 = __shfl(cv, k + 3);
            s0 += bf2f(soc1[c0 * 64 + d]);
            if (k + 1 < km) s1a += bf2f(soc1[c1 * 64 + d]);
            if (k + 2 < km) s2a += bf2f(soc1[c2 * 64 + d]);
            if (k + 3 < km) s3a += bf2f(soc1[c3 * 64 + d]);
        }
        for (int j = j0 + 64; j < j0 + dg; ++j)        // deg>64 tail (rare)
            s0 += bf2f(soc1[csr[j] * 64 + d]);
        float s2 = ((s0 + s1a) + (s2a + s3a)) / fmaxf((float)dg, 1.0f);
        float ud = (float)udeg[u];
        float usw = 1.0f - ud / (ud + 1e-8f);       // f32: 1 if deg==0 else 0
        float ue = uemb[u * 64 + d];
        float s1 = bf2f(soc1[u * 64 + d]);
        float r1 = usw * ue + bf2f(ru1c[b * 64 + d]);
        float r2 = usw * r1 + bf2f(ru2c[b * 64 + d]);
        float fu = ue + 0.5f * (s1 + r1) + 0.5f * (s2 + r2);
        float iv = iemb[it * 64 + d];
        out[NBATCH + b * 64 + d]               = fu;
        out[NBATCH + NBATCH * 64 + b * 64 + d] = iv;
        float p = fu * iv;
        #pragma unroll
        for (int o = 32; o > 0; o >>= 1) p += __shfl_down(p, o);
        if (d == 0) out[b] = 1.0f / (1.0f + __expf(-p));
    }
}

extern "C" void kernel_launch(void* const* d_in, const int* in_sizes, int n_in,
                              void* d_out, int out_size, void* d_ws, size_t ws_size,
                              hipStream_t stream) {
    const float* uemb  = (const float*)d_in[0];
    const float* iemb  = (const float*)d_in[1];
    const int*   users = (const int*)d_in[2];
    const int*   items = (const int*)d_in[3];
    const int*   ssrc  = (const int*)d_in[4];
    const int*   sdst  = (const int*)d_in[5];
    const int*   lu    = (const int*)d_in[6];
    const int*   li    = (const int*)d_in[7];
    float* out = (float*)d_out;

    if (ws_size < (size_t)WS_FLOATS * 4) return;  // would show absmax==0.5 diagnostic

    int*           W      = (int*)d_ws;
    int*           gcnt   = W + OFF_GC;
    int*           gbase  = W + OFF_GB;
    int*           gcur   = W + OFF_GCUR;
    unsigned*      bits   = (unsigned*)(W + OFF_BITS);
    unsigned char* needed = (unsigned char*)(W + OFF_NEED);
    int*           ideg   = W + OFF_IDEG;
    int*           udeg   = W + OFF_UDEG;
    int*           sdeg   = W + OFF_SDEG;
    int*           istart = W + OFF_ISTART;
    int*           ustart = W + OFF_USTART;
    int*           sstart = W + OFF_SSTART;
    int*           partLI = W + OFF_PARTLI;
    int*           partLU = W + OFF_PARTLU;
    int*           partSD = W + OFF_PARTSD;
    u16*           uembh  = (u16*)(W + OFF_UEMBH);   // overlays part* (post-passD)
    int*           csrli  = W + OFF_CSRLI;
    int*           csrlu  = W + OFF_CSRLU;
    int*           csrsd  = W + OFF_CSRSD;
    u16*           ri1    = (u16*)(W + OFF_RI1);
    u16*           soc1   = (u16*)(W + OFF_SOC1);    // overlays csrli/csrlu/ri1
    u16*           ru1c   = (u16*)(W + OFF_RU1C);
    u16*           ru2c   = (u16*)(W + OFF_RU2C);

    hipMemsetAsync(d_ws, 0, (size_t)OFF_ZEND * 4, stream);   // gcnt + bits + needed

    const int B = 256;

    // CSR build (bucket-partitioned, chunked writes, LDS-bitmask membership)
    k_slot<<<(NBATCH + B - 1) / B, B, 0, stream>>>(users, bits, needed);
    k_passA<<<NBLK_E, B, 0, stream>>>(lu, li, sdst, ssrc, bits, gcnt, needed);
    k_passB<<<1, B, 0, stream>>>(gcnt, gbase, gcur);
    k_passC<<<NBLK_E, B, 0, stream>>>(lu, li, sdst, ssrc, bits, gcur,
                                      partLI, partLU, partSD);
    k_passD<<<588, B, 0, stream>>>(gcnt, gbase, partLI, partLU, partSD,
                                   csrli, csrlu, csrsd, ideg, udeg, sdeg,
                                   istart, ustart, sstart);

    // bf16 shadow of uemb (part* now dead)
    k_cvt<<<(NUSERS * 16 + B - 1) / B, B, 0, stream>>>(uemb, uembh);

    // rating branch (persistent grid-stride gathers)
    k_gather_item<<<GGRID, B, 0, stream>>>(iemb, (const unsigned*)uembh,
                                           csrli, istart, ideg, (unsigned*)ri1);
    k_batch_rat<<<GGRID, B, 0, stream>>>(users, iemb, ri1, csrlu, ustart,
                                         udeg, ru1c, ru2c);
    // social branch (soc1 overlay only covers dead csrli/csrlu/ri1)
    k_gather_soc<<<GGRID, B, 0, stream>>>((const unsigned*)uembh, csrsd,
                                          sstart, sdeg, needed, (unsigned*)soc1);

    // fused batch social mean + epilogue
    k_final<<<GGRID, B, 0, stream>>>(users, items, uemb, iemb, soc1,
                                     csrsd, sstart, sdeg, ru1c, ru2c, udeg, out);
}

// Round 2
// 273.992 us; speedup vs baseline: 1.0834x; 1.0834x over previous
//
#include <hip/hip_runtime.h>
#include <hip/hip_bf16.h>

#define NUSERS 100000
#define NITEMS 50000
#define NEDGE  1000000
#define NBATCH 16384
#define CAP_LU 320000     // filtered like-edges of batch users; expected ~164K (2x margin)
#define EPB    2048       // edges per block in passA/passC (8 per thread)
#define NBLK_E ((NEDGE + EPB - 1) / EPB)   // 489
#define NBW    3125       // NUSERS/32 bitmask words
#define GGRID  2048       // persistent grid: 256 CU x 8 blocks (256thr) = full residency

// ---- workspace layout, units of 4 bytes; total 8,979,016 units = 35.9 MB ----
// Overlays:
//   uembh (bf16 uemb shadow, 3.2M units) = [530,440 .. 3,730,440): covers
//     partLI+partLU+partSD (dead after passD; k_cvt runs after passD) + pad.
//   soc1  (bf16, 3.2M units) = [3,730,440 .. 6,930,440): covers csrli (dead after
//     gather_item) + csrlu + ri1 (dead after batch_rat) + pad. gather_soc runs
//     after batch_rat. csrsd/ru1c/ru2c live beyond both overlays.
#define OFF_GC     0                          // 256*3 bucket counts (memset 0)
#define OFF_GB     768
#define OFF_GCUR   1536
#define OFF_BITS   2304                       // 3136 u32 batch-membership bitmask
#define OFF_NEED   (OFF_BITS + 3136)          // NUSERS bytes = 25000 units
#define OFF_ZEND   (OFF_NEED + NUSERS / 4)    // 30,440 end of memset-0 region
#define OFF_IDEG   OFF_ZEND
#define OFF_UDEG   (OFF_IDEG + NITEMS)
#define OFF_SDEG   (OFF_UDEG + NUSERS)
#define OFF_ISTART (OFF_SDEG + NUSERS)
#define OFF_USTART (OFF_ISTART + NITEMS)
#define OFF_SSTART (OFF_USTART + NUSERS)
#define OFF_PARTLI (OFF_SSTART + NUSERS)      // 530,440
#define OFF_PARTLU (OFF_PARTLI + NEDGE)
#define OFF_PARTSD (OFF_PARTLU + CAP_LU)
#define OFF_UEMBH  OFF_PARTLI                 // NUSERS*32 units (bf16 shadow)
#define OFF_CSRLI  (OFF_UEMBH + NUSERS * 32)  // 3,730,440
#define OFF_CSRLU  (OFF_CSRLI + NEDGE)
#define OFF_RI1    (OFF_CSRLU + CAP_LU)       // NITEMS*32 units (bf16)
#define OFF_SOC1   OFF_CSRLI                  // NUSERS*32 units overlay
#define OFF_CSRSD  (OFF_SOC1 + NUSERS * 32)   // 6,930,440 (LIVE till k_final)
#define OFF_RU1C   (OFF_CSRSD + NEDGE)        // NBATCH*64 bf16 = 524,288 units
#define OFF_RU2C   (OFF_RU1C + NBATCH * 32)
#define WS_FLOATS  (OFF_RU2C + NBATCH * 32)   // 8,979,016

typedef unsigned short u16;

__device__ __forceinline__ float bf2f(u16 h) {
    union { unsigned u; float f; } c; c.u = ((unsigned)h) << 16; return c.f;
}
__device__ __forceinline__ u16 f2bf(float f) {
    union { float f; unsigned u; } c; c.f = f;
    unsigned r = c.u + 0x7fffu + ((c.u >> 16) & 1u);   // RNE
    return (u16)(r >> 16);
}
__device__ __forceinline__ void acc2(unsigned w, float& a0, float& a1) {
    a0 += bf2f((u16)(w & 0xffff));
    a1 += bf2f((u16)(w >> 16));
}
__device__ __forceinline__ void acc8(uint4 w, float* a) {
    acc2(w.x, a[0], a[1]); acc2(w.y, a[2], a[3]);
    acc2(w.z, a[4], a[5]); acc2(w.w, a[6], a[7]);
}

// ---- batch membership: bitmask + needed flags ----
__global__ void k_slot(const int* __restrict__ users, unsigned* __restrict__ bits,
                       unsigned char* __restrict__ needed) {
    int b = blockIdx.x * blockDim.x + threadIdx.x;
    if (b < NBATCH) {
        int u = users[b];
        atomicOr(&bits[u >> 5], 1u << (u & 31));
        needed[u] = 1;
    }
}

// ---- pass A: per-block LDS bucket histograms; membership via LDS bitmask ----
__global__ void k_passA(const int* __restrict__ lu, const int* __restrict__ li,
                        const int* __restrict__ sd, const int* __restrict__ ss,
                        const unsigned* __restrict__ bits, int* __restrict__ gcnt,
                        unsigned char* __restrict__ needed) {
    __shared__ int lc[768];
    __shared__ unsigned sbits[NBW];
    int t = threadIdx.x;
    for (int k = t; k < 768; k += 256) lc[k] = 0;
    for (int k = t; k < NBW; k += 256) sbits[k] = bits[k];
    __syncthreads();
    int base = blockIdx.x * EPB;
    int end = base + EPB; if (end > NEDGE) end = NEDGE;
    for (int e = base + t; e < end; e += 256) {
        int item = li[e], a = lu[e], d = sd[e];
        atomicAdd(&lc[item >> 9], 1);                        // list0: by item
        if ((sbits[a >> 5] >> (a & 31)) & 1)                 // list1: batch users
            atomicAdd(&lc[256 + (a >> 9)], 1);
        atomicAdd(&lc[512 + (d >> 9)], 1);                   // list2: by dst user
        if ((sbits[d >> 5] >> (d & 31)) & 1)                 // soc1 needed at source
            needed[ss[e]] = 1;
    }
    __syncthreads();
    for (int k = t; k < 768; k += 256)
        if (lc[k]) atomicAdd(&gcnt[k], lc[k]);
}

// ---- pass B: one block; 3 exclusive scans of 256 bucket counts ----
__global__ void k_passB(const int* __restrict__ gcnt, int* __restrict__ gbase,
                        int* __restrict__ gcur) {
    __shared__ int s[256];
    int t = threadIdx.x;
    for (int j = 0; j < 3; ++j) {
        int v = gcnt[j * 256 + t];
        s[t] = v;
        __syncthreads();
        for (int o = 1; o < 256; o <<= 1) {
            int x = (t >= o) ? s[t - o] : 0;
            __syncthreads();
            s[t] += x;
            __syncthreads();
        }
        int ex = s[t] - v;
        gbase[j * 256 + t] = ex;
        gcur[j * 256 + t] = ex;
        __syncthreads();
    }
}

// ---- pass C: partition edges into per-bucket chunks; membership via LDS
//      bitmask in phase 1, cached in a register mask for phase 2 ----
__global__ void k_passC(const int* __restrict__ lu, const int* __restrict__ li,
                        const int* __restrict__ sd, const int* __restrict__ ss,
                        const unsigned* __restrict__ bits, int* __restrict__ gcur,
                        int* __restrict__ partLI, int* __restrict__ partLU,
                        int* __restrict__ partSD) {
    __shared__ int lc[768];   // local counts, then rank counters
    __shared__ int go[768];   // this block's global chunk offsets
    __shared__ unsigned sbits[NBW];
    int t = threadIdx.x;
    for (int k = t; k < 768; k += 256) lc[k] = 0;
    for (int k = t; k < NBW; k += 256) sbits[k] = bits[k];
    __syncthreads();
    int base = blockIdx.x * EPB;
    int end = base + EPB; if (end > NEDGE) end = NEDGE;
    unsigned mask = 0;        // bit i: edge (base + i*256 + t) belongs to a batch user
    int i = 0;
    for (int e = base + t; e < end; e += 256, ++i) {
        int item = li[e], a = lu[e], d = sd[e];
        atomicAdd(&lc[item >> 9], 1);
        if ((sbits[a >> 5] >> (a & 31)) & 1) {
            atomicAdd(&lc[256 + (a >> 9)], 1);
            mask |= (1u << i);
        }
        atomicAdd(&lc[512 + (d >> 9)], 1);
    }
    __syncthreads();
    for (int k = t; k < 768; k += 256) {
        go[k] = lc[k] ? atomicAdd(&gcur[k], lc[k]) : 0;
        lc[k] = 0;
    }
    __syncthreads();
    i = 0;
    for (int e = base + t; e < end; e += 256, ++i) {
        int item = li[e], a = lu[e], d = sd[e], s_ = ss[e];
        int b0 = item >> 9;
        int r0 = atomicAdd(&lc[b0], 1);
        partLI[go[b0] + r0] = (a << 9) | (item & 511);
        if (mask & (1u << i)) {
            int b1 = 256 + (a >> 9);
            int r1 = atomicAdd(&lc[b1], 1);
            partLU[go[b1] + r1] = (item << 9) | (a & 511);
        }
        int b2 = 512 + (d >> 9);
        int r2 = atomicAdd(&lc[b2], 1);
        partSD[go[b2] + r2] = (s_ << 9) | (d & 511);
    }
}

// ---- pass D: one block per bucket; count/scan -> deg/start + rank-scatter ----
__global__ void k_passD(const int* __restrict__ gcnt, const int* __restrict__ gbase,
                        const int* __restrict__ partLI, const int* __restrict__ partLU,
                        const int* __restrict__ partSD, int* __restrict__ csrli,
                        int* __restrict__ csrlu, int* __restrict__ csrsd,
                        int* __restrict__ ideg, int* __restrict__ udeg,
                        int* __restrict__ sdeg, int* __restrict__ istart,
                        int* __restrict__ ustart, int* __restrict__ sstart) {
    __shared__ int lcnt[512], lstart[512], sb[2][512];
    int t = threadIdx.x;
    int blk = blockIdx.x, list, b;
    const int* part; int* csr; int* deg; int* start; int n;
    if (blk < 196)      { list = 0; b = blk;       part = partLI; csr = csrli; deg = ideg; start = istart; n = NITEMS; }
    else if (blk < 392) { list = 1; b = blk - 196; part = partLU; csr = csrlu; deg = udeg; start = ustart; n = NUSERS; }
    else                { list = 2; b = blk - 392; part = partSD; csr = csrsd; deg = sdeg; start = sstart; n = NUSERS; }
    int base = gbase[list * 256 + b], cnt = gcnt[list * 256 + b];
    int node0 = b << 9;
    int M = n - node0; if (M > 512) M = 512; if (M < 0) M = 0;

    lcnt[t] = 0; lcnt[t + 256] = 0;
    __syncthreads();
    for (int i = t; i < cnt; i += 256) atomicAdd(&lcnt[part[base + i] & 511], 1);
    __syncthreads();
    sb[0][t] = lcnt[t]; sb[0][t + 256] = lcnt[t + 256];
    __syncthreads();
    int pp = 0;
    for (int o = 1; o < 512; o <<= 1) {
        int np = pp ^ 1;
        for (int k = t; k < 512; k += 256) {
            int v = sb[pp][k];
            if (k >= o) v += sb[pp][k - o];
            sb[np][k] = v;
        }
        __syncthreads();
        pp = np;
    }
    for (int k = t; k < 512; k += 256) {
        int ex = sb[pp][k] - lcnt[k];       // exclusive scan
        lstart[k] = ex;
        if (k < M) { deg[node0 + k] = lcnt[k]; start[node0 + k] = base + ex; }
    }
    __syncthreads();
    lcnt[t] = 0; lcnt[t + 256] = 0;
    __syncthreads();
    for (int i = t; i < cnt; i += 256) {
        int p = part[base + i];
        int nl = p & 511;
        int r = atomicAdd(&lcnt[nl], 1);
        csr[base + lstart[nl] + r] = p >> 9;  // window stays in one XCD's L2
    }
}

// ---- bf16 shadow of uemb (runs after passD; overlays dead part*) ----
__global__ void k_cvt(const float* __restrict__ src, u16* __restrict__ dst) {
    int t = blockIdx.x * 256 + threadIdx.x;
    if (t >= NUSERS * 16) return;                 // 16 float4 per row
    float4 v = ((const float4*)src)[t];
    ushort4 o;
    o.x = f2bf(v.x); o.y = f2bf(v.y); o.z = f2bf(v.z); o.w = f2bf(v.w);
    ((ushort4*)dst)[t] = o;
}

// ---- epilogue helpers (value args -> stays in registers, rule #20) ----
__device__ __forceinline__ void item_store(int n, int dg, const float* __restrict__ iemb,
                                           unsigned* __restrict__ ri1, int l8,
                                           float s0, float s1, float s2, float s3,
                                           float s4, float s5, float s6, float s7) {
    float dgf = (float)dg;
    float inv = 1.0f / fmaxf(dgf, 1.0f);
    float sw  = 1.0f - dgf / (dgf + 1e-8f);
    float4 e0 = ((const float4*)(iemb + n * 64))[l8 * 2];
    float4 e1 = ((const float4*)(iemb + n * 64))[l8 * 2 + 1];
    uint4 o;
    o.x = (unsigned)f2bf(sw * e0.x + s0 * inv) | ((unsigned)f2bf(sw * e0.y + s1 * inv) << 16);
    o.y = (unsigned)f2bf(sw * e0.z + s2 * inv) | ((unsigned)f2bf(sw * e0.w + s3 * inv) << 16);
    o.z = (unsigned)f2bf(sw * e1.x + s4 * inv) | ((unsigned)f2bf(sw * e1.y + s5 * inv) << 16);
    o.w = (unsigned)f2bf(sw * e1.z + s6 * inv) | ((unsigned)f2bf(sw * e1.w + s7 * inv) << 16);
    ((uint4*)(ri1 + n * 32))[l8] = o;
}
__device__ __forceinline__ void soc_store(int n, int dg, unsigned* __restrict__ soc1, int l8,
                                          float s0, float s1, float s2, float s3,
                                          float s4, float s5, float s6, float s7) {
    float inv = 1.0f / fmaxf((float)dg, 1.0f);
    uint4 o;
    o.x = (unsigned)f2bf(s0 * inv) | ((unsigned)f2bf(s1 * inv) << 16);
    o.y = (unsigned)f2bf(s2 * inv) | ((unsigned)f2bf(s3 * inv) << 16);
    o.z = (unsigned)f2bf(s4 * inv) | ((unsigned)f2bf(s5 * inv) << 16);
    o.w = (unsigned)f2bf(s6 * inv) | ((unsigned)f2bf(s7 * inv) << 16);
    ((uint4*)(soc1 + n * 32))[l8] = o;
}

// ---- ri1 = i_sw*iemb + mean(uembh[liking users]); TWO items per wave.
//      dwordx4 row gathers: 8 lanes per 128B row -> one load inst = 1KB = 8 rows.
//      Loads are UNCONDITIONAL with clamped broadcast index (only the acc is
//      predicated) so the compiler clusters 4x1KB in flight per wave. ----
__global__ void k_gather_item(const float* __restrict__ iemb,
                              const unsigned* __restrict__ uh32,
                              const int* __restrict__ csr, const int* __restrict__ istart,
                              const int* __restrict__ ideg, unsigned* __restrict__ ri1) {
    int lane = threadIdx.x & 63;
    int wid  = blockIdx.x * 4 + (threadIdx.x >> 6);
    int nw   = gridDim.x * 4;
    int g = lane >> 3, l8 = lane & 7;
    for (int nA = wid * 2; nA < NITEMS; nA += nw * 2) {
        int nB = nA + 1;                          // NITEMS even -> always valid
        int jA = istart[nA], dA = ideg[nA];
        int jB = istart[nB], dB = ideg[nB];
        int cA = (lane < dA) ? csr[jA + lane] : 0;
        int cB = (lane < dB) ? csr[jB + lane] : 0;
        int kmA = dA < 64 ? dA : 64;
        int kmB = dB < 64 ? dB : 64;
        int clA = kmA > 0 ? kmA - 1 : 0;
        int clB = kmB > 0 ? kmB - 1 : 0;
        int km  = kmA > kmB ? kmA : kmB;
        float aA[8] = {0.f,0.f,0.f,0.f,0.f,0.f,0.f,0.f};
        float aB[8] = {0.f,0.f,0.f,0.f,0.f,0.f,0.f,0.f};
        for (int k = 0; k < km; k += 16) {
            int q0 = k + g, q1 = k + 8 + g;
            int iA0 = q0 < kmA ? q0 : clA;
            int iA1 = q1 < kmA ? q1 : clA;
            int iB0 = q0 < kmB ? q0 : clB;
            int iB1 = q1 < kmB ? q1 : clB;
            int rA0 = __shfl(cA, iA0), rA1 = __shfl(cA, iA1);
            int rB0 = __shfl(cB, iB0), rB1 = __shfl(cB, iB1);
            uint4 wA0 = *(const uint4*)(uh32 + rA0 * 32 + l8 * 4);
            uint4 wA1 = *(const uint4*)(uh32 + rA1 * 32 + l8 * 4);
            uint4 wB0 = *(const uint4*)(uh32 + rB0 * 32 + l8 * 4);
            uint4 wB1 = *(const uint4*)(uh32 + rB1 * 32 + l8 * 4);
            if (q0 < kmA) acc8(wA0, aA);
            if (q1 < kmA) acc8(wA1, aA);
            if (q0 < kmB) acc8(wB0, aB);
            if (q1 < kmB) acc8(wB1, aB);
        }
        for (int k = 64; k < dA; k += 8) {        // deg>64 tail (rare)
            int q = k + g; int idx = q < dA ? q : dA - 1;
            int r = csr[jA + idx];
            uint4 w = *(const uint4*)(uh32 + r * 32 + l8 * 4);
            if (q < dA) acc8(w, aA);
        }
        for (int k = 64; k < dB; k += 8) {
            int q = k + g; int idx = q < dB ? q : dB - 1;
            int r = csr[jB + idx];
            uint4 w = *(const uint4*)(uh32 + r * 32 + l8 * 4);
            if (q < dB) acc8(w, aB);
        }
        #pragma unroll
        for (int off = 8; off <= 32; off <<= 1) {
            #pragma unroll
            for (int m = 0; m < 8; ++m) {
                aA[m] += __shfl_xor(aA[m], off);
                aB[m] += __shfl_xor(aB[m], off);
            }
        }
        if (g == 0)
            item_store(nA, dA, iemb, ri1, l8, aA[0],aA[1],aA[2],aA[3],aA[4],aA[5],aA[6],aA[7]);
        else if (g == 1)
            item_store(nB, dB, iemb, ri1, l8, aB[0],aB[1],aB[2],aB[3],aB[4],aB[5],aB[6],aB[7]);
    }
}

// ---- batch rating means: ru1c[b]=mean(iemb[li]), ru2c[b]=mean(ri1[li]).
//      Clamped unconditional loads, 8 rows x 2 streams = 16 loads in flight. ----
__global__ void k_batch_rat(const int* __restrict__ users, const float* __restrict__ iemb,
                            const u16* __restrict__ ri1, const int* __restrict__ csr,
                            const int* __restrict__ ustart, const int* __restrict__ udeg,
                            u16* __restrict__ ru1c, u16* __restrict__ ru2c) {
    int lane = threadIdx.x & 63;
    int wid  = blockIdx.x * 4 + (threadIdx.x >> 6);
    int nw   = gridDim.x * 4;
    for (int b = wid; b < NBATCH; b += nw) {
        int u = users[b];
        int j0 = ustart[u], dg = udeg[u];
        int cv = (lane < dg) ? csr[j0 + lane] : 0;
        int km = dg < 64 ? dg : 64;
        int cl = km > 0 ? km - 1 : 0;
        float p0=0.f,p1=0.f,p2=0.f,p3=0.f, q0=0.f,q1=0.f,q2=0.f,q3=0.f;
        for (int k = 0; k < km; k += 8) {
            int x1 = k+1 < km ? k+1 : cl, x2 = k+2 < km ? k+2 : cl;
            int x3 = k+3 < km ? k+3 : cl, x4 = k+4 < km ? k+4 : cl;
            int x5 = k+5 < km ? k+5 : cl, x6 = k+6 < km ? k+6 : cl;
            int x7 = k+7 < km ? k+7 : cl;
            int i0 = __shfl(cv, k),  i1 = __shfl(cv, x1);
            int i2 = __shfl(cv, x2), i3 = __shfl(cv, x3);
            int i4 = __shfl(cv, x4), i5 = __shfl(cv, x5);
            int i6 = __shfl(cv, x6), i7 = __shfl(cv, x7);
            float t0 = iemb[i0 * 64 + lane], t1 = iemb[i1 * 64 + lane];
            float t2 = iemb[i2 * 64 + lane], t3 = iemb[i3 * 64 + lane];
            float t4 = iemb[i4 * 64 + lane], t5 = iemb[i5 * 64 + lane];
            float t6 = iemb[i6 * 64 + lane], t7 = iemb[i7 * 64 + lane];
            float r0 = bf2f(ri1[i0 * 64 + lane]), r1 = bf2f(ri1[i1 * 64 + lane]);
            float r2 = bf2f(ri1[i2 * 64 + lane]), r3 = bf2f(ri1[i3 * 64 + lane]);
            float r4 = bf2f(ri1[i4 * 64 + lane]), r5 = bf2f(ri1[i5 * 64 + lane]);
            float r6 = bf2f(ri1[i6 * 64 + lane]), r7 = bf2f(ri1[i7 * 64 + lane]);
            p0 += t0; q0 += r0;
            if (k+1 < km) { p1 += t1; q1 += r1; }
            if (k+2 < km) { p2 += t2; q2 += r2; }
            if (k+3 < km) { p3 += t3; q3 += r3; }
            if (k+4 < km) { p0 += t4; q0 += r4; }
            if (k+5 < km) { p1 += t5; q1 += r5; }
            if (k+6 < km) { p2 += t6; q2 += r6; }
            if (k+7 < km) { p3 += t7; q3 += r7; }
        }
        for (int j = j0 + 64; j < j0 + dg; ++j) {      // deg>64 tail (rare)
            int i0 = csr[j];
            p0 += iemb[i0 * 64 + lane]; q0 += bf2f(ri1[i0 * 64 + lane]);
        }
        float inv = 1.0f / fmaxf((float)dg, 1.0f);
        ru1c[b * 64 + lane] = f2bf(((p0 + p1) + (p2 + p3)) * inv);
        ru2c[b * 64 + lane] = f2bf(((q0 + q1) + (q2 + q3)) * inv);
    }
}

// ---- soc1 = mean(uembh[social sources]); only where needed; TWO nodes per
//      wave; dwordx4 gathers, clamped unconditional loads as gather_item. ----
__global__ void k_gather_soc(const unsigned* __restrict__ uh32,
                             const int* __restrict__ csr, const int* __restrict__ sstart,
                             const int* __restrict__ sdeg,
                             const unsigned char* __restrict__ needed,
                             unsigned* __restrict__ soc1) {
    int lane = threadIdx.x & 63;
    int wid  = blockIdx.x * 4 + (threadIdx.x >> 6);
    int nw   = gridDim.x * 4;
    int g = lane >> 3, l8 = lane & 7;
    for (int nA = wid * 2; nA < NUSERS; nA += nw * 2) {
        int nB = nA + 1;                          // NUSERS even -> always valid
        unsigned short nd = *(const unsigned short*)(needed + nA);   // nA even
        if (!nd) continue;                        // neither row ever read
        int needA = nd & 0xff, needB = nd >> 8;
        int jA = sstart[nA], dA = needA ? sdeg[nA] : 0;
        int jB = sstart[nB], dB = needB ? sdeg[nB] : 0;
        int cA = (lane < dA) ? csr[jA + lane] : 0;
        int cB = (lane < dB) ? csr[jB + lane] : 0;
        int kmA = dA < 64 ? dA : 64;
        int kmB = dB < 64 ? dB : 64;
        int clA = kmA > 0 ? kmA - 1 : 0;
        int clB = kmB > 0 ? kmB - 1 : 0;
        int km  = kmA > kmB ? kmA : kmB;
        float aA[8] = {0.f,0.f,0.f,0.f,0.f,0.f,0.f,0.f};
        float aB[8] = {0.f,0.f,0.f,0.f,0.f,0.f,0.f,0.f};
        for (int k = 0; k < km; k += 16) {
            int q0 = k + g, q1 = k + 8 + g;
            int iA0 = q0 < kmA ? q0 : clA;
            int iA1 = q1 < kmA ? q1 : clA;
            int iB0 = q0 < kmB ? q0 : clB;
            int iB1 = q1 < kmB ? q1 : clB;
            int rA0 = __shfl(cA, iA0), rA1 = __shfl(cA, iA1);
            int rB0 = __shfl(cB, iB0), rB1 = __shfl(cB, iB1);
            uint4 wA0 = *(const uint4*)(uh32 + rA0 * 32 + l8 * 4);
            uint4 wA1 = *(const uint4*)(uh32 + rA1 * 32 + l8 * 4);
            uint4 wB0 = *(const uint4*)(uh32 + rB0 * 32 + l8 * 4);
            uint4 wB1 = *(const uint4*)(uh32 + rB1 * 32 + l8 * 4);
            if (q0 < kmA) acc8(wA0, aA);
            if (q1 < kmA) acc8(wA1, aA);
            if (q0 < kmB) acc8(wB0, aB);
            if (q1 < kmB) acc8(wB1, aB);
        }
        for (int k = 64; k < dA; k += 8) {        // deg>64 tail (rare)
            int q = k + g; int idx = q < dA ? q : dA - 1;
            int r = csr[jA + idx];
            uint4 w = *(const uint4*)(uh32 + r * 32 + l8 * 4);
            if (q < dA) acc8(w, aA);
        }
        for (int k = 64; k < dB; k += 8) {
            int q = k + g; int idx = q < dB ? q : dB - 1;
            int r = csr[jB + idx];
            uint4 w = *(const uint4*)(uh32 + r * 32 + l8 * 4);
            if (q < dB) acc8(w, aB);
        }
        #pragma unroll
        for (int off = 8; off <= 32; off <<= 1) {
            #pragma unroll
            for (int m = 0; m < 8; ++m) {
                aA[m] += __shfl_xor(aA[m], off);
                aB[m] += __shfl_xor(aB[m], off);
            }
        }
        if (g == 0 && needA)
            soc_store(nA, dA, soc1, l8, aA[0],aA[1],aA[2],aA[3],aA[4],aA[5],aA[6],aA[7]);
        else if (g == 1 && needB)
            soc_store(nB, dB, soc1, l8, aB[0],aB[1],aB[2],aB[3],aB[4],aB[5],aB[6],aB[7]);
    }
}

// ---- fused batch social mean + epilogue; clamped unconditional loads, 8 deep ----
__global__ void k_final(const int* __restrict__ users, const int* __restrict__ items,
                        const float* __restrict__ uemb, const float* __restrict__ iemb,
                        const u16* __restrict__ soc1, const int* __restrict__ csr,
                        const int* __restrict__ sstart, const int* __restrict__ sdeg,
                        const u16* __restrict__ ru1c, const u16* __restrict__ ru2c,
                        const int* __restrict__ udeg, float* __restrict__ out) {
    int d   = threadIdx.x & 63;
    int wid = blockIdx.x * 4 + (threadIdx.x >> 6);
    int nw  = gridDim.x * 4;
    for (int b = wid; b < NBATCH; b += nw) {
        int u = users[b], it = items[b];
        int j0 = sstart[u], dg = sdeg[u];
        int cv = (d < dg) ? csr[j0 + d] : 0;
        int km = dg < 64 ? dg : 64;
        int cl = km > 0 ? km - 1 : 0;
        float s0=0.f, s1a=0.f, s2a=0.f, s3a=0.f;
        for (int k = 0; k < km; k += 8) {
            int x1 = k+1 < km ? k+1 : cl, x2 = k+2 < km ? k+2 : cl;
            int x3 = k+3 < km ? k+3 : cl, x4 = k+4 < km ? k+4 : cl;
            int x5 = k+5 < km ? k+5 : cl, x6 = k+6 < km ? k+6 : cl;
            int x7 = k+7 < km ? k+7 : cl;
            int c0 = __shfl(cv, k),  c1 = __shfl(cv, x1);
            int c2 = __shfl(cv, x2), c3 = __shfl(cv, x3);
            int c4 = __shfl(cv, x4), c5 = __shfl(cv, x5);
            int c6 = __shfl(cv, x6), c7 = __shfl(cv, x7);
            float f0 = bf2f(soc1[c0 * 64 + d]), f1 = bf2f(soc1[c1 * 64 + d]);
            float f2 = bf2f(soc1[c2 * 64 + d]), f3 = bf2f(soc1[c3 * 64 + d]);
            float f4 = bf2f(soc1[c4 * 64 + d]), f5 = bf2f(soc1[c5 * 64 + d]);
            float f6 = bf2f(soc1[c6 * 64 + d]), f7 = bf2f(soc1[c7 * 64 + d]);
            s0 += f0;
            if (k+1 < km) s1a += f1;
            if (k+2 < km) s2a += f2;
            if (k+3 < km) s3a += f3;
            if (k+4 < km) s0  += f4;
            if (k+5 < km) s1a += f5;
            if (k+6 < km) s2a += f6;
            if (k+7 < km) s3a += f7;
        }
        for (int j = j0 + 64; j < j0 + dg; ++j)        // deg>64 tail (rare)
            s0 += bf2f(soc1[csr[j] * 64 + d]);
        float s2 = ((s0 + s1a) + (s2a + s3a)) / fmaxf((float)dg, 1.0f);
        float ud = (float)udeg[u];
        float usw = 1.0f - ud / (ud + 1e-8f);       // f32: 1 if deg==0 else 0
        float ue = uemb[u * 64 + d];
        float s1 = bf2f(soc1[u * 64 + d]);
        float r1 = usw * ue + bf2f(ru1c[b * 64 + d]);
        float r2 = usw * r1 + bf2f(ru2c[b * 64 + d]);
        float fu = ue + 0.5f * (s1 + r1) + 0.5f * (s2 + r2);
        float iv = iemb[it * 64 + d];
        out[NBATCH + b * 64 + d]               = fu;
        out[NBATCH + NBATCH * 64 + b * 64 + d] = iv;
        float p = fu * iv;
        #pragma unroll
        for (int o = 32; o > 0; o >>= 1) p += __shfl_down(p, o);
        if (d == 0) out[b] = 1.0f / (1.0f + __expf(-p));
    }
}

extern "C" void kernel_launch(void* const* d_in, const int* in_sizes, int n_in,
                              void* d_out, int out_size, void* d_ws, size_t ws_size,
                              hipStream_t stream) {
    const float* uemb  = (const float*)d_in[0];
    const float* iemb  = (const float*)d_in[1];
    const int*   users = (const int*)d_in[2];
    const int*   items = (const int*)d_in[3];
    const int*   ssrc  = (const int*)d_in[4];
    const int*   sdst  = (const int*)d_in[5];
    const int*   lu    = (const int*)d_in[6];
    const int*   li    = (const int*)d_in[7];
    float* out = (float*)d_out;

    if (ws_size < (size_t)WS_FLOATS * 4) return;  // would show absmax==0.5 diagnostic

    int*           W      = (int*)d_ws;
    int*           gcnt   = W + OFF_GC;
    int*           gbase  = W + OFF_GB;
    int*           gcur   = W + OFF_GCUR;
    unsigned*      bits   = (unsigned*)(W + OFF_BITS);
    unsigned char* needed = (unsigned char*)(W + OFF_NEED);
    int*           ideg   = W + OFF_IDEG;
    int*           udeg   = W + OFF_UDEG;
    int*           sdeg   = W + OFF_SDEG;
    int*           istart = W + OFF_ISTART;
    int*           ustart = W + OFF_USTART;
    int*           sstart = W + OFF_SSTART;
    int*           partLI = W + OFF_PARTLI;
    int*           partLU = W + OFF_PARTLU;
    int*           partSD = W + OFF_PARTSD;
    u16*           uembh  = (u16*)(W + OFF_UEMBH);   // overlays part* (post-passD)
    int*           csrli  = W + OFF_CSRLI;
    int*           csrlu  = W + OFF_CSRLU;
    int*           csrsd  = W + OFF_CSRSD;
    u16*           ri1    = (u16*)(W + OFF_RI1);
    u16*           soc1   = (u16*)(W + OFF_SOC1);    // overlays csrli/csrlu/ri1
    u16*           ru1c   = (u16*)(W + OFF_RU1C);
    u16*           ru2c   = (u16*)(W + OFF_RU2C);

    hipMemsetAsync(d_ws, 0, (size_t)OFF_ZEND * 4, stream);   // gcnt + bits + needed

    const int B = 256;

    // CSR build (bucket-partitioned, chunked writes, LDS-bitmask membership)
    k_slot<<<(NBATCH + B - 1) / B, B, 0, stream>>>(users, bits, needed);
    k_passA<<<NBLK_E, B, 0, stream>>>(lu, li, sdst, ssrc, bits, gcnt, needed);
    k_passB<<<1, B, 0, stream>>>(gcnt, gbase, gcur);
    k_passC<<<NBLK_E, B, 0, stream>>>(lu, li, sdst, ssrc, bits, gcur,
                                      partLI, partLU, partSD);
    k_passD<<<588, B, 0, stream>>>(gcnt, gbase, partLI, partLU, partSD,
                                   csrli, csrlu, csrsd, ideg, udeg, sdeg,
                                   istart, ustart, sstart);

    // bf16 shadow of uemb (part* now dead)
    k_cvt<<<(NUSERS * 16 + B - 1) / B, B, 0, stream>>>(uemb, uembh);

    // rating branch (persistent grid-stride gathers)
    k_gather_item<<<GGRID, B, 0, stream>>>(iemb, (const unsigned*)uembh,
                                           csrli, istart, ideg, (unsigned*)ri1);
    k_batch_rat<<<GGRID, B, 0, stream>>>(users, iemb, ri1, csrlu, ustart,
                                         udeg, ru1c, ru2c);
    // social branch (soc1 overlay only covers dead csrli/csrlu/ri1)
    k_gather_soc<<<GGRID, B, 0, stream>>>((const unsigned*)uembh, csrsd,
                                          sstart, sdeg, needed, (unsigned*)soc1);

    // fused batch social mean + epilogue
    k_final<<<GGRID, B, 0, stream>>>(users, items, uemb, iemb, soc1,
                                     csrsd, sstart, sdeg, ru1c, ru2c, udeg, out);
}

// Round 3
// 252.609 us; speedup vs baseline: 1.1751x; 1.0846x over previous
//
#include <hip/hip_runtime.h>
#include <hip/hip_bf16.h>

#define NUSERS 100000
#define NITEMS 50000
#define NEDGE  1000000
#define NBATCH 16384
#define CAP_LU 320000     // filtered like-edges of batch users; expected ~164K (2x margin)
#define EPB    2048       // edges per block in passA/passC (8 per thread)
#define NBLK_E ((NEDGE + EPB - 1) / EPB)   // 489
#define NBW    3125       // NUSERS/32 bitmask words
#define GGRID  2048       // persistent grid: 256 CU x 8 blocks (256thr) = full residency

// ---- workspace layout, units of 4 bytes; total 10,850,464 units = 43.4 MB ----
// (ws is 256 MiB per the harness poison fill -> no need for tight overlays.)
// ALL bf16 row arrays (uembh/ri1/soc1) are 128-B aligned: each 64-dim bf16 row
// is exactly one 128-B cache line (the old layout was +32B skewed -> 3x64B
// sectors per row gather).
// Single remaining overlay: uembh over part* (dead after passD; k_cvt runs after).
#define OFF_GC     0                          // 256*3 bucket counts (memset 0)
#define OFF_GB     768
#define OFF_GCUR   1536
#define OFF_BITS   2304                       // 3136 u32 batch-membership bitmask
#define OFF_NEED   (OFF_BITS + 3136)          // NUSERS bytes = 25000 units
#define OFF_ZEND   (OFF_NEED + NUSERS / 4)    // 30,440 end of memset-0 region
#define OFF_IDEG   OFF_ZEND
#define OFF_UDEG   (OFF_IDEG + NITEMS)
#define OFF_SDEG   (OFF_UDEG + NUSERS)
#define OFF_ISTART (OFF_SDEG + NUSERS)
#define OFF_USTART (OFF_ISTART + NITEMS)
#define OFF_SSTART (OFF_USTART + NUSERS)
#define OFF_PARTLI 530464                     // AL32(530,440) -> 128-B aligned
#define OFF_PARTLU (OFF_PARTLI + NEDGE)
#define OFF_PARTSD (OFF_PARTLU + CAP_LU)      // part end 2,850,464
#define OFF_UEMBH  OFF_PARTLI                 // NUSERS*32 units (bf16 shadow), 128-B aligned
#define OFF_CSRLI  (OFF_UEMBH + NUSERS * 32)  // 3,730,464
#define OFF_CSRLU  (OFF_CSRLI + NEDGE)
#define OFF_CSRSD  (OFF_CSRLU + CAP_LU)
#define OFF_RI1    (OFF_CSRSD + NEDGE)        // 6,050,464 (mod 32 == 0)
#define OFF_SOC1   (OFF_RI1 + NITEMS * 32)    // 7,650,464 (mod 32 == 0)
#define WS_FLOATS  (OFF_SOC1 + NUSERS * 32)   // 10,850,464

typedef unsigned short u16;

__device__ __forceinline__ float bf2f(u16 h) {
    union { unsigned u; float f; } c; c.u = ((unsigned)h) << 16; return c.f;
}
__device__ __forceinline__ u16 f2bf(float f) {
    union { float f; unsigned u; } c; c.f = f;
    unsigned r = c.u + 0x7fffu + ((c.u >> 16) & 1u);   // RNE
    return (u16)(r >> 16);
}
__device__ __forceinline__ void acc2(unsigned w, float& a0, float& a1) {
    a0 += bf2f((u16)(w & 0xffff));
    a1 += bf2f((u16)(w >> 16));
}
__device__ __forceinline__ void acc8(uint4 w, float* a) {
    acc2(w.x, a[0], a[1]); acc2(w.y, a[2], a[3]);
    acc2(w.z, a[4], a[5]); acc2(w.w, a[6], a[7]);
}

// ---- batch membership: bitmask + needed flags ----
__global__ void k_slot(const int* __restrict__ users, unsigned* __restrict__ bits,
                       unsigned char* __restrict__ needed) {
    int b = blockIdx.x * blockDim.x + threadIdx.x;
    if (b < NBATCH) {
        int u = users[b];
        atomicOr(&bits[u >> 5], 1u << (u & 31));
        needed[u] = 1;
    }
}

// ---- pass A: per-block LDS bucket histograms; membership via LDS bitmask ----
__global__ void k_passA(const int* __restrict__ lu, const int* __restrict__ li,
                        const int* __restrict__ sd, const int* __restrict__ ss,
                        const unsigned* __restrict__ bits, int* __restrict__ gcnt,
                        unsigned char* __restrict__ needed) {
    __shared__ int lc[768];
    __shared__ unsigned sbits[NBW];
    int t = threadIdx.x;
    for (int k = t; k < 768; k += 256) lc[k] = 0;
    for (int k = t; k < NBW; k += 256) sbits[k] = bits[k];
    __syncthreads();
    int base = blockIdx.x * EPB;
    int end = base + EPB; if (end > NEDGE) end = NEDGE;
    for (int e = base + t; e < end; e += 256) {
        int item = li[e], a = lu[e], d = sd[e];
        atomicAdd(&lc[item >> 9], 1);                        // list0: by item
        if ((sbits[a >> 5] >> (a & 31)) & 1)                 // list1: batch users
            atomicAdd(&lc[256 + (a >> 9)], 1);
        atomicAdd(&lc[512 + (d >> 9)], 1);                   // list2: by dst user
        if ((sbits[d >> 5] >> (d & 31)) & 1)                 // soc1 needed at source
            needed[ss[e]] = 1;
    }
    __syncthreads();
    for (int k = t; k < 768; k += 256)
        if (lc[k]) atomicAdd(&gcnt[k], lc[k]);
}

// ---- pass B: one block; 3 exclusive scans of 256 bucket counts ----
__global__ void k_passB(const int* __restrict__ gcnt, int* __restrict__ gbase,
                        int* __restrict__ gcur) {
    __shared__ int s[256];
    int t = threadIdx.x;
    for (int j = 0; j < 3; ++j) {
        int v = gcnt[j * 256 + t];
        s[t] = v;
        __syncthreads();
        for (int o = 1; o < 256; o <<= 1) {
            int x = (t >= o) ? s[t - o] : 0;
            __syncthreads();
            s[t] += x;
            __syncthreads();
        }
        int ex = s[t] - v;
        gbase[j * 256 + t] = ex;
        gcur[j * 256 + t] = ex;
        __syncthreads();
    }
}

// ---- pass C: partition edges into per-bucket chunks; membership via LDS
//      bitmask in phase 1, cached in a register mask for phase 2 ----
__global__ void k_passC(const int* __restrict__ lu, const int* __restrict__ li,
                        const int* __restrict__ sd, const int* __restrict__ ss,
                        const unsigned* __restrict__ bits, int* __restrict__ gcur,
                        int* __restrict__ partLI, int* __restrict__ partLU,
                        int* __restrict__ partSD) {
    __shared__ int lc[768];   // local counts, then rank counters
    __shared__ int go[768];   // this block's global chunk offsets
    __shared__ unsigned sbits[NBW];
    int t = threadIdx.x;
    for (int k = t; k < 768; k += 256) lc[k] = 0;
    for (int k = t; k < NBW; k += 256) sbits[k] = bits[k];
    __syncthreads();
    int base = blockIdx.x * EPB;
    int end = base + EPB; if (end > NEDGE) end = NEDGE;
    unsigned mask = 0;        // bit i: edge (base + i*256 + t) belongs to a batch user
    int i = 0;
    for (int e = base + t; e < end; e += 256, ++i) {
        int item = li[e], a = lu[e], d = sd[e];
        atomicAdd(&lc[item >> 9], 1);
        if ((sbits[a >> 5] >> (a & 31)) & 1) {
            atomicAdd(&lc[256 + (a >> 9)], 1);
            mask |= (1u << i);
        }
        atomicAdd(&lc[512 + (d >> 9)], 1);
    }
    __syncthreads();
    for (int k = t; k < 768; k += 256) {
        go[k] = lc[k] ? atomicAdd(&gcur[k], lc[k]) : 0;
        lc[k] = 0;
    }
    __syncthreads();
    i = 0;
    for (int e = base + t; e < end; e += 256, ++i) {
        int item = li[e], a = lu[e], d = sd[e], s_ = ss[e];
        int b0 = item >> 9;
        int r0 = atomicAdd(&lc[b0], 1);
        partLI[go[b0] + r0] = (a << 9) | (item & 511);
        if (mask & (1u << i)) {
            int b1 = 256 + (a >> 9);
            int r1 = atomicAdd(&lc[b1], 1);
            partLU[go[b1] + r1] = (item << 9) | (a & 511);
        }
        int b2 = 512 + (d >> 9);
        int r2 = atomicAdd(&lc[b2], 1);
        partSD[go[b2] + r2] = (s_ << 9) | (d & 511);
    }
}

// ---- pass D: one block per bucket; count/scan -> deg/start + rank-scatter ----
__global__ void k_passD(const int* __restrict__ gcnt, const int* __restrict__ gbase,
                        const int* __restrict__ partLI, const int* __restrict__ partLU,
                        const int* __restrict__ partSD, int* __restrict__ csrli,
                        int* __restrict__ csrlu, int* __restrict__ csrsd,
                        int* __restrict__ ideg, int* __restrict__ udeg,
                        int* __restrict__ sdeg, int* __restrict__ istart,
                        int* __restrict__ ustart, int* __restrict__ sstart) {
    __shared__ int lcnt[512], lstart[512], sb[2][512];
    int t = threadIdx.x;
    int blk = blockIdx.x, list, b;
    const int* part; int* csr; int* deg; int* start; int n;
    if (blk < 196)      { list = 0; b = blk;       part = partLI; csr = csrli; deg = ideg; start = istart; n = NITEMS; }
    else if (blk < 392) { list = 1; b = blk - 196; part = partLU; csr = csrlu; deg = udeg; start = ustart; n = NUSERS; }
    else                { list = 2; b = blk - 392; part = partSD; csr = csrsd; deg = sdeg; start = sstart; n = NUSERS; }
    int base = gbase[list * 256 + b], cnt = gcnt[list * 256 + b];
    int node0 = b << 9;
    int M = n - node0; if (M > 512) M = 512; if (M < 0) M = 0;

    lcnt[t] = 0; lcnt[t + 256] = 0;
    __syncthreads();
    for (int i = t; i < cnt; i += 256) atomicAdd(&lcnt[part[base + i] & 511], 1);
    __syncthreads();
    sb[0][t] = lcnt[t]; sb[0][t + 256] = lcnt[t + 256];
    __syncthreads();
    int pp = 0;
    for (int o = 1; o < 512; o <<= 1) {
        int np = pp ^ 1;
        for (int k = t; k < 512; k += 256) {
            int v = sb[pp][k];
            if (k >= o) v += sb[pp][k - o];
            sb[np][k] = v;
        }
        __syncthreads();
        pp = np;
    }
    for (int k = t; k < 512; k += 256) {
        int ex = sb[pp][k] - lcnt[k];       // exclusive scan
        lstart[k] = ex;
        if (k < M) { deg[node0 + k] = lcnt[k]; start[node0 + k] = base + ex; }
    }
    __syncthreads();
    lcnt[t] = 0; lcnt[t + 256] = 0;
    __syncthreads();
    for (int i = t; i < cnt; i += 256) {
        int p = part[base + i];
        int nl = p & 511;
        int r = atomicAdd(&lcnt[nl], 1);
        csr[base + lstart[nl] + r] = p >> 9;  // window stays in one XCD's L2
    }
}

// ---- bf16 shadow of uemb (runs after passD; overlays dead part*) ----
__global__ void k_cvt(const float* __restrict__ src, u16* __restrict__ dst) {
    int t = blockIdx.x * 256 + threadIdx.x;
    if (t >= NUSERS * 16) return;                 // 16 float4 per row
    float4 v = ((const float4*)src)[t];
    ushort4 o;
    o.x = f2bf(v.x); o.y = f2bf(v.y); o.z = f2bf(v.z); o.w = f2bf(v.w);
    ((ushort4*)dst)[t] = o;
}

// ---- epilogue helpers (value args -> stays in registers, rule #20) ----
__device__ __forceinline__ void item_store(int n, int dg, const float* __restrict__ iemb,
                                           unsigned* __restrict__ ri1, int l8,
                                           const float* __restrict__ s) {
    float dgf = (float)dg;
    float inv = 1.0f / fmaxf(dgf, 1.0f);
    float sw  = 1.0f - dgf / (dgf + 1e-8f);
    float4 e0 = ((const float4*)(iemb + n * 64))[l8 * 2];
    float4 e1 = ((const float4*)(iemb + n * 64))[l8 * 2 + 1];
    uint4 o;
    o.x = (unsigned)f2bf(sw * e0.x + s[0] * inv) | ((unsigned)f2bf(sw * e0.y + s[1] * inv) << 16);
    o.y = (unsigned)f2bf(sw * e0.z + s[2] * inv) | ((unsigned)f2bf(sw * e0.w + s[3] * inv) << 16);
    o.z = (unsigned)f2bf(sw * e1.x + s[4] * inv) | ((unsigned)f2bf(sw * e1.y + s[5] * inv) << 16);
    o.w = (unsigned)f2bf(sw * e1.z + s[6] * inv) | ((unsigned)f2bf(sw * e1.w + s[7] * inv) << 16);
    ((uint4*)(ri1 + n * 32))[l8] = o;
}
__device__ __forceinline__ void soc_store(int n, int dg, unsigned* __restrict__ soc1, int l8,
                                          const float* __restrict__ s) {
    float inv = 1.0f / fmaxf((float)dg, 1.0f);
    uint4 o;
    o.x = (unsigned)f2bf(s[0] * inv) | ((unsigned)f2bf(s[1] * inv) << 16);
    o.y = (unsigned)f2bf(s[2] * inv) | ((unsigned)f2bf(s[3] * inv) << 16);
    o.z = (unsigned)f2bf(s[4] * inv) | ((unsigned)f2bf(s[5] * inv) << 16);
    o.w = (unsigned)f2bf(s[6] * inv) | ((unsigned)f2bf(s[7] * inv) << 16);
    ((uint4*)(soc1 + n * 32))[l8] = o;
}

// ---- core: gather-mean of two bf16 rowsets. dwordx4 row gathers (8 lanes per
//      128-B row -> one load inst = 1KB = 8 rows), UNCONDITIONAL clamped loads
//      so the compiler clusters 4x1KB in flight; butterfly-reduce across the
//      8 lane-groups at the end. ----
__device__ __forceinline__ void gather_pair(const unsigned* __restrict__ uh32,
                                            const int* __restrict__ csr,
                                            int jA, int dA, int jB, int dB,
                                            int lane, int g, int l8,
                                            float* __restrict__ aA,
                                            float* __restrict__ aB) {
    int cA = (lane < dA) ? csr[jA + lane] : 0;
    int cB = (lane < dB) ? csr[jB + lane] : 0;
    int kmA = dA < 64 ? dA : 64;
    int kmB = dB < 64 ? dB : 64;
    int clA = kmA > 0 ? kmA - 1 : 0;
    int clB = kmB > 0 ? kmB - 1 : 0;
    int km  = kmA > kmB ? kmA : kmB;
    for (int k = 0; k < km; k += 16) {
        int q0 = k + g, q1 = k + 8 + g;
        int iA0 = q0 < kmA ? q0 : clA;
        int iA1 = q1 < kmA ? q1 : clA;
        int iB0 = q0 < kmB ? q0 : clB;
        int iB1 = q1 < kmB ? q1 : clB;
        int rA0 = __shfl(cA, iA0), rA1 = __shfl(cA, iA1);
        int rB0 = __shfl(cB, iB0), rB1 = __shfl(cB, iB1);
        uint4 wA0 = *(const uint4*)(uh32 + rA0 * 32 + l8 * 4);
        uint4 wA1 = *(const uint4*)(uh32 + rA1 * 32 + l8 * 4);
        uint4 wB0 = *(const uint4*)(uh32 + rB0 * 32 + l8 * 4);
        uint4 wB1 = *(const uint4*)(uh32 + rB1 * 32 + l8 * 4);
        if (q0 < kmA) acc8(wA0, aA);
        if (q1 < kmA) acc8(wA1, aA);
        if (q0 < kmB) acc8(wB0, aB);
        if (q1 < kmB) acc8(wB1, aB);
    }
    for (int k = 64; k < dA; k += 8) {        // deg>64 tail (rare)
        int q = k + g; int idx = q < dA ? q : dA - 1;
        int r = csr[jA + idx];
        uint4 w = *(const uint4*)(uh32 + r * 32 + l8 * 4);
        if (q < dA) acc8(w, aA);
    }
    for (int k = 64; k < dB; k += 8) {
        int q = k + g; int idx = q < dB ? q : dB - 1;
        int r = csr[jB + idx];
        uint4 w = *(const uint4*)(uh32 + r * 32 + l8 * 4);
        if (q < dB) acc8(w, aB);
    }
    #pragma unroll
    for (int off = 8; off <= 32; off <<= 1) {
        #pragma unroll
        for (int m = 0; m < 8; ++m) {
            aA[m] += __shfl_xor(aA[m], off);
            aB[m] += __shfl_xor(aB[m], off);
        }
    }
}

// ---- fused gather: items (ri1) and social users (soc1) in ONE kernel.
//      They are data-independent (both read only uembh + their CSR) -- fusing
//      overlaps the two latency-bound phases and removes a launch tail. ----
__global__ void k_gather_fused(const float* __restrict__ iemb,
                               const unsigned* __restrict__ uh32,
                               const int* __restrict__ csrli, const int* __restrict__ istart,
                               const int* __restrict__ ideg, unsigned* __restrict__ ri1,
                               const int* __restrict__ csrsd, const int* __restrict__ sstart,
                               const int* __restrict__ sdeg,
                               const unsigned char* __restrict__ needed,
                               unsigned* __restrict__ soc1) {
    int lane = threadIdx.x & 63;
    int wid  = blockIdx.x * 4 + (threadIdx.x >> 6);
    int nw   = gridDim.x * 4;
    int g = lane >> 3, l8 = lane & 7;
    const int NPI = NITEMS / 2;               // 25000 item pairs
    const int NP  = NPI + NUSERS / 2;         // + 50000 soc pairs
    for (int w = wid; w < NP; w += nw) {
        if (w < NPI) {
            int nA = w * 2, nB = nA + 1;
            int jA = istart[nA], dA = ideg[nA];
            int jB = istart[nB], dB = ideg[nB];
            float aA[8] = {0.f,0.f,0.f,0.f,0.f,0.f,0.f,0.f};
            float aB[8] = {0.f,0.f,0.f,0.f,0.f,0.f,0.f,0.f};
            gather_pair(uh32, csrli, jA, dA, jB, dB, lane, g, l8, aA, aB);
            if (g == 0)      item_store(nA, dA, iemb, ri1, l8, aA);
            else if (g == 1) item_store(nB, dB, iemb, ri1, l8, aB);
        } else {
            int nA = (w - NPI) * 2, nB = nA + 1;
            unsigned short nd = *(const unsigned short*)(needed + nA);   // nA even
            if (!nd) continue;                // neither row ever read
            int needA = nd & 0xff, needB = nd >> 8;
            int jA = sstart[nA], dA = needA ? sdeg[nA] : 0;
            int jB = sstart[nB], dB = needB ? sdeg[nB] : 0;
            float aA[8] = {0.f,0.f,0.f,0.f,0.f,0.f,0.f,0.f};
            float aB[8] = {0.f,0.f,0.f,0.f,0.f,0.f,0.f,0.f};
            gather_pair(uh32, csrsd, jA, dA, jB, dB, lane, g, l8, aA, aB);
            if (g == 0 && needA)      soc_store(nA, dA, soc1, l8, aA);
            else if (g == 1 && needB) soc_store(nB, dB, soc1, l8, aB);
        }
    }
}

// ---- fused epilogue: rating means (iemb/ri1 over like-list) + social mean
//      (soc1 over social in-list) + final combine, all per batch element.
//      ru1/ru2 never round-trip through memory (stay f32 in registers). ----
__global__ void k_final2(const int* __restrict__ users, const int* __restrict__ items,
                         const float* __restrict__ uemb, const float* __restrict__ iemb,
                         const u16* __restrict__ ri1, const int* __restrict__ csrlu,
                         const int* __restrict__ ustart, const int* __restrict__ udeg,
                         const u16* __restrict__ soc1, const int* __restrict__ csrsd,
                         const int* __restrict__ sstart, const int* __restrict__ sdeg,
                         float* __restrict__ out) {
    int d   = threadIdx.x & 63;
    int wid = blockIdx.x * 4 + (threadIdx.x >> 6);
    int nw  = gridDim.x * 4;
    for (int b = wid; b < NBATCH; b += nw) {
        int u = users[b], it = items[b];
        int ju = ustart[u], du = udeg[u];
        int js = sstart[u], ds = sdeg[u];
        int cvU = (d < du) ? csrlu[ju + d] : 0;
        int cvS = (d < ds) ? csrsd[js + d] : 0;
        // ---- rating means over like-list ----
        int kmu = du < 64 ? du : 64;
        int clu = kmu > 0 ? kmu - 1 : 0;
        float p0=0.f,p1=0.f,p2=0.f,p3=0.f, q0=0.f,q1=0.f,q2=0.f,q3=0.f;
        for (int k = 0; k < kmu; k += 8) {
            int x1 = k+1 < kmu ? k+1 : clu, x2 = k+2 < kmu ? k+2 : clu;
            int x3 = k+3 < kmu ? k+3 : clu, x4 = k+4 < kmu ? k+4 : clu;
            int x5 = k+5 < kmu ? k+5 : clu, x6 = k+6 < kmu ? k+6 : clu;
            int x7 = k+7 < kmu ? k+7 : clu;
            int i0 = __shfl(cvU, k),  i1 = __shfl(cvU, x1);
            int i2 = __shfl(cvU, x2), i3 = __shfl(cvU, x3);
            int i4 = __shfl(cvU, x4), i5 = __shfl(cvU, x5);
            int i6 = __shfl(cvU, x6), i7 = __shfl(cvU, x7);
            float t0 = iemb[i0 * 64 + d], t1 = iemb[i1 * 64 + d];
            float t2 = iemb[i2 * 64 + d], t3 = iemb[i3 * 64 + d];
            float t4 = iemb[i4 * 64 + d], t5 = iemb[i5 * 64 + d];
            float t6 = iemb[i6 * 64 + d], t7 = iemb[i7 * 64 + d];
            float r0 = bf2f(ri1[i0 * 64 + d]), r1 = bf2f(ri1[i1 * 64 + d]);
            float r2 = bf2f(ri1[i2 * 64 + d]), r3 = bf2f(ri1[i3 * 64 + d]);
            float r4 = bf2f(ri1[i4 * 64 + d]), r5 = bf2f(ri1[i5 * 64 + d]);
            float r6 = bf2f(ri1[i6 * 64 + d]), r7 = bf2f(ri1[i7 * 64 + d]);
            p0 += t0; q0 += r0;
            if (k+1 < kmu) { p1 += t1; q1 += r1; }
            if (k+2 < kmu) { p2 += t2; q2 += r2; }
            if (k+3 < kmu) { p3 += t3; q3 += r3; }
            if (k+4 < kmu) { p0 += t4; q0 += r4; }
            if (k+5 < kmu) { p1 += t5; q1 += r5; }
            if (k+6 < kmu) { p2 += t6; q2 += r6; }
            if (k+7 < kmu) { p3 += t7; q3 += r7; }
        }
        for (int j = ju + 64; j < ju + du; ++j) {      // deg>64 tail (rare)
            int i0 = csrlu[j];
            p0 += iemb[i0 * 64 + d]; q0 += bf2f(ri1[i0 * 64 + d]);
        }
        // ---- social mean over in-list ----
        int kms = ds < 64 ? ds : 64;
        int cls = kms > 0 ? kms - 1 : 0;
        float s0=0.f, s1a=0.f, s2a=0.f, s3a=0.f;
        for (int k = 0; k < kms; k += 8) {
            int x1 = k+1 < kms ? k+1 : cls, x2 = k+2 < kms ? k+2 : cls;
            int x3 = k+3 < kms ? k+3 : cls, x4 = k+4 < kms ? k+4 : cls;
            int x5 = k+5 < kms ? k+5 : cls, x6 = k+6 < kms ? k+6 : cls;
            int x7 = k+7 < kms ? k+7 : cls;
            int c0 = __shfl(cvS, k),  c1 = __shfl(cvS, x1);
            int c2 = __shfl(cvS, x2), c3 = __shfl(cvS, x3);
            int c4 = __shfl(cvS, x4), c5 = __shfl(cvS, x5);
            int c6 = __shfl(cvS, x6), c7 = __shfl(cvS, x7);
            float f0 = bf2f(soc1[c0 * 64 + d]), f1 = bf2f(soc1[c1 * 64 + d]);
            float f2 = bf2f(soc1[c2 * 64 + d]), f3 = bf2f(soc1[c3 * 64 + d]);
            float f4 = bf2f(soc1[c4 * 64 + d]), f5 = bf2f(soc1[c5 * 64 + d]);
            float f6 = bf2f(soc1[c6 * 64 + d]), f7 = bf2f(soc1[c7 * 64 + d]);
            s0 += f0;
            if (k+1 < kms) s1a += f1;
            if (k+2 < kms) s2a += f2;
            if (k+3 < kms) s3a += f3;
            if (k+4 < kms) s0  += f4;
            if (k+5 < kms) s1a += f5;
            if (k+6 < kms) s2a += f6;
            if (k+7 < kms) s3a += f7;
        }
        for (int j = js + 64; j < js + ds; ++j)        // deg>64 tail (rare)
            s0 += bf2f(soc1[csrsd[j] * 64 + d]);
        // ---- combine ----
        float invU = 1.0f / fmaxf((float)du, 1.0f);
        float ru1 = ((p0 + p1) + (p2 + p3)) * invU;
        float ru2 = ((q0 + q1) + (q2 + q3)) * invU;
        float s2 = ((s0 + s1a) + (s2a + s3a)) / fmaxf((float)ds, 1.0f);
        float ud = (float)du;
        float usw = 1.0f - ud / (ud + 1e-8f);       // f32: 1 if deg==0 else 0
        float ue = uemb[u * 64 + d];
        float s1 = bf2f(soc1[u * 64 + d]);
        float r1 = usw * ue + ru1;
        float r2 = usw * r1 + ru2;
        float fu = ue + 0.5f * (s1 + r1) + 0.5f * (s2 + r2);
        float iv = iemb[it * 64 + d];
        out[NBATCH + b * 64 + d]               = fu;
        out[NBATCH + NBATCH * 64 + b * 64 + d] = iv;
        float p = fu * iv;
        #pragma unroll
        for (int o = 32; o > 0; o >>= 1) p += __shfl_down(p, o);
        if (d == 0) out[b] = 1.0f / (1.0f + __expf(-p));
    }
}

extern "C" void kernel_launch(void* const* d_in, const int* in_sizes, int n_in,
                              void* d_out, int out_size, void* d_ws, size_t ws_size,
                              hipStream_t stream) {
    const float* uemb  = (const float*)d_in[0];
    const float* iemb  = (const float*)d_in[1];
    const int*   users = (const int*)d_in[2];
    const int*   items = (const int*)d_in[3];
    const int*   ssrc  = (const int*)d_in[4];
    const int*   sdst  = (const int*)d_in[5];
    const int*   lu    = (const int*)d_in[6];
    const int*   li    = (const int*)d_in[7];
    float* out = (float*)d_out;

    if (ws_size < (size_t)WS_FLOATS * 4) return;  // would show absmax==0.5 diagnostic

    int*           W      = (int*)d_ws;
    int*           gcnt   = W + OFF_GC;
    int*           gbase  = W + OFF_GB;
    int*           gcur   = W + OFF_GCUR;
    unsigned*      bits   = (unsigned*)(W + OFF_BITS);
    unsigned char* needed = (unsigned char*)(W + OFF_NEED);
    int*           ideg   = W + OFF_IDEG;
    int*           udeg   = W + OFF_UDEG;
    int*           sdeg   = W + OFF_SDEG;
    int*           istart = W + OFF_ISTART;
    int*           ustart = W + OFF_USTART;
    int*           sstart = W + OFF_SSTART;
    int*           partLI = W + OFF_PARTLI;
    int*           partLU = W + OFF_PARTLU;
    int*           partSD = W + OFF_PARTSD;
    u16*           uembh  = (u16*)(W + OFF_UEMBH);   // overlays part* (post-passD)
    int*           csrli  = W + OFF_CSRLI;
    int*           csrlu  = W + OFF_CSRLU;
    int*           csrsd  = W + OFF_CSRSD;
    u16*           ri1    = (u16*)(W + OFF_RI1);
    u16*           soc1   = (u16*)(W + OFF_SOC1);

    hipMemsetAsync(d_ws, 0, (size_t)OFF_ZEND * 4, stream);   // gcnt + bits + needed

    const int B = 256;

    // CSR build (bucket-partitioned, chunked writes, LDS-bitmask membership)
    k_slot<<<(NBATCH + B - 1) / B, B, 0, stream>>>(users, bits, needed);
    k_passA<<<NBLK_E, B, 0, stream>>>(lu, li, sdst, ssrc, bits, gcnt, needed);
    k_passB<<<1, B, 0, stream>>>(gcnt, gbase, gcur);
    k_passC<<<NBLK_E, B, 0, stream>>>(lu, li, sdst, ssrc, bits, gcur,
                                      partLI, partLU, partSD);
    k_passD<<<588, B, 0, stream>>>(gcnt, gbase, partLI, partLU, partSD,
                                   csrli, csrlu, csrsd, ideg, udeg, sdeg,
                                   istart, ustart, sstart);

    // bf16 shadow of uemb (part* now dead)
    k_cvt<<<(NUSERS * 16 + B - 1) / B, B, 0, stream>>>(uemb, uembh);

    // fused item + social gathers (independent; overlap latency)
    k_gather_fused<<<GGRID, B, 0, stream>>>(iemb, (const unsigned*)uembh,
                                            csrli, istart, ideg, (unsigned*)ri1,
                                            csrsd, sstart, sdeg, needed,
                                            (unsigned*)soc1);

    // fused rating means + social mean + epilogue
    k_final2<<<GGRID, B, 0, stream>>>(users, items, uemb, iemb, ri1, csrlu,
                                      ustart, udeg, soc1, csrsd, sstart, sdeg, out);
}